// Round 1
// 352.246 us; speedup vs baseline: 1.0415x; 1.0415x over previous
//
#include <hip/hip_runtime.h>
#include <math.h>

#define NN 65536        // nodes
#define NE 524288       // edges (without self loops)
#define D 128
#define ED 32
#define NEG_SLOPE 0.2f

typedef short bf16x8 __attribute__((ext_vector_type(8)));
typedef float f32x4 __attribute__((ext_vector_type(4)));
typedef unsigned short ushort_t;

__device__ __forceinline__ float leaky(float x) { return x > 0.f ? x : NEG_SLOPE * x; }
__device__ __forceinline__ float gelu_exact(float x) {
    return 0.5f * x * (1.f + erff(x * 0.70710678118654752440f));
}
__device__ __forceinline__ unsigned short bf16_rne(float x) {
    unsigned u = __float_as_uint(x);
    return (unsigned short)((u + 0x7FFFu + ((u >> 16) & 1u)) >> 16);
}
__device__ __forceinline__ void unpack8(int4 r, float* f) {
    unsigned u0 = (unsigned)r.x, u1 = (unsigned)r.y, u2 = (unsigned)r.z, u3 = (unsigned)r.w;
    f[0] = __uint_as_float(u0 << 16); f[1] = __uint_as_float(u0 & 0xFFFF0000u);
    f[2] = __uint_as_float(u1 << 16); f[3] = __uint_as_float(u1 & 0xFFFF0000u);
    f[4] = __uint_as_float(u2 << 16); f[5] = __uint_as_float(u2 & 0xFFFF0000u);
    f[6] = __uint_as_float(u3 << 16); f[7] = __uint_as_float(u3 & 0xFFFF0000u);
}

// ---------------- edge precompute + CSR build ----------------

__global__ void k_wvec(const float* __restrict__ We, const float* __restrict__ ae, float* __restrict__ wvec) {
    int t = threadIdx.x;
    if (t < 3 * ED) {
        int l = t / ED, k = t % ED;
        const float* w = We + (long)(l * ED + k) * D;
        const float* a = ae + (long)l * D;
        float s = 0.f;
        #pragma unroll
        for (int i = 0; i < D; ++i) s += w[i] * a[i];
        wvec[t] = s;
    }
}

// Edge-order ale (coalesced) + degree histogram fused (atomic latency hidden
// under the BW-bound ea read).
__global__ void k_ale_hist(const float* __restrict__ ea, const float* __restrict__ wvec,
                           const int* __restrict__ dstArr, int* __restrict__ deg,
                           float* __restrict__ ale0, float* __restrict__ ale1,
                           float* __restrict__ ale2) {
    int e = blockIdx.x * 256 + threadIdx.x;
    atomicAdd(&deg[dstArr[e]], 1);
    const float4* row = (const float4*)(ea + (long)e * ED);
    const float4* w0 = (const float4*)(wvec);
    const float4* w1 = (const float4*)(wvec + ED);
    const float4* w2 = (const float4*)(wvec + 2 * ED);
    float s0 = 0.f, s1 = 0.f, s2 = 0.f;
    #pragma unroll
    for (int i = 0; i < ED / 4; ++i) {
        float4 v = row[i];
        float4 a = w0[i], b = w1[i], c = w2[i];
        s0 += v.x * a.x + v.y * a.y + v.z * a.z + v.w * a.w;
        s1 += v.x * b.x + v.y * b.y + v.z * b.z + v.w * b.w;
        s2 += v.x * c.x + v.y * c.y + v.z * c.z + v.w * c.w;
    }
    ale0[e] = s0;
    ale1[e] = s1;
    ale2[e] = s2;
}

__global__ void k_scan1(const int* __restrict__ deg, int* __restrict__ rp, int* __restrict__ bsum) {
    __shared__ int s[256];
    int t = threadIdx.x;
    int i = blockIdx.x * 256 + t;
    int v = deg[i];
    s[t] = v;
    __syncthreads();
    #pragma unroll
    for (int off = 1; off < 256; off <<= 1) {
        int x = (t >= off) ? s[t - off] : 0;
        __syncthreads();
        s[t] += x;
        __syncthreads();
    }
    rp[i] = s[t] - v;
    if (t == 255) bsum[blockIdx.x] = s[t];
}

__global__ void k_scan2(const int* __restrict__ bsum, int* __restrict__ bscan, int* __restrict__ rp) {
    __shared__ int s[256];
    int t = threadIdx.x;
    int v = bsum[t];
    s[t] = v;
    __syncthreads();
    #pragma unroll
    for (int off = 1; off < 256; off <<= 1) {
        int x = (t >= off) ? s[t - off] : 0;
        __syncthreads();
        s[t] += x;
        __syncthreads();
    }
    bscan[t] = s[t] - v;
    if (t == 255) rp[NN] = s[t];
}

__global__ void k_scan3(int* __restrict__ rp, const int* __restrict__ bscan, int* __restrict__ cursor) {
    int i = blockIdx.x * 256 + threadIdx.x;
    int v = rp[i] + bscan[blockIdx.x];
    rp[i] = v;
    cursor[i] = v;
}

// Scatter packed records; 4 edges per thread for 4x memory-level parallelism
// on the random atomic + random 16B store chain. All reads coalesced.
__global__ void k_scatter4(const int* __restrict__ srcArr, const int* __restrict__ dstArr,
                           int* __restrict__ cursor, const float* __restrict__ ale0,
                           const float* __restrict__ ale1, const float* __restrict__ ale2,
                           int4* __restrict__ edata) {
    int base = blockIdx.x * 1024 + threadIdx.x;
    int e[4], d[4], p[4];
    #pragma unroll
    for (int i = 0; i < 4; ++i) e[i] = base + 256 * i;
    #pragma unroll
    for (int i = 0; i < 4; ++i) d[i] = dstArr[e[i]];
    #pragma unroll
    for (int i = 0; i < 4; ++i) p[i] = atomicAdd(&cursor[d[i]], 1);
    #pragma unroll
    for (int i = 0; i < 4; ++i) {
        edata[p[i]] = make_int4(srcArr[e[i]], __float_as_int(ale0[e[i]]),
                                __float_as_int(ale1[e[i]]), __float_as_int(ale2[e[i]]));
    }
}

// Pack W (128x128 fp32) into MFMA fragment order, split bf16 hi/lo.
// (16x16x32 A- and B-fragment lane layouts are identical, so this pack is
// used as the FIRST mfma operand after the swap.)
__global__ void k_wpack(const float* __restrict__ Ws, short* __restrict__ Whp, short* __restrict__ Wlp) {
    int t = blockIdx.x * 256 + threadIdx.x;
    if (t >= 3 * 4 * 4 * 128) return;
    int n = t & 127;
    int q = (t >> 7) & 3;
    int ks = (t >> 9) & 3;
    int l = t >> 11;
    const float* w = Ws + (size_t)l * D * D;
    size_t obase = (size_t)l * D * D + ((size_t)((ks * 4 + q) * 128) + n) * 8;
    #pragma unroll
    for (int j = 0; j < 8; ++j) {
        float x = w[(size_t)(ks * 32 + q * 8 + j) * D + n];
        unsigned short hb = bf16_rne(x);
        float hf = __uint_as_float(((unsigned)hb) << 16);
        Whp[obase + j] = (short)hb;
        Wlp[obase + j] = (short)bf16_rne(x - hf);
    }
}

// ---------------- per-layer kernels ----------------

// C = A @ W via split-bf16 MFMA with SWAPPED operands: mfma(W_frag, h_frag)
// so acc holds row=l16, 4 consecutive cols per reg quad. A read as fp32 and
// split to bf16 hi/lo inline (same bytes as pre-split hi+lo, kills k_splitx).
// B staged in LDS (32KB, two halves). One wave = 32 rows x 128 cols.
// Epilogue: Hb written bf16 via per-wave LDS transpose -> coalesced 16B
// stores; als/ald per-lane dot + 2 shuffles, coalesced write.
__global__ __launch_bounds__(256) void k_gemm_mfma(const float* __restrict__ A,
        const short* __restrict__ Whp, const short* __restrict__ Wlp,
        const float* __restrict__ a_s, const float* __restrict__ a_d,
        ushort_t* __restrict__ Hb, float* __restrict__ als, float* __restrict__ ald) {
    __shared__ int4 Bs[2048];   // 32KB: [0..1023]=hi, [1024..2047]=lo; reused for epilogue transpose
    int t = threadIdx.x;
    int wave = t >> 6, lane = t & 63;
    int l16 = lane & 15, q = lane >> 4;
    int rows_base = blockIdx.x * 128 + wave * 32;

    const int4* wh4 = (const int4*)Whp;
    const int4* wl4 = (const int4*)Wlp;
    const short* bsh = (const short*)Bs;
    const short* bsl = (const short*)(Bs + 1024);

    f32x4 acc[2][8] = {};
    #pragma unroll
    for (int h2 = 0; h2 < 2; ++h2) {
        if (h2) __syncthreads();
        #pragma unroll
        for (int i = 0; i < 4; ++i) {
            Bs[t + 256 * i] = wh4[h2 * 1024 + t + 256 * i];
            Bs[1024 + t + 256 * i] = wl4[h2 * 1024 + t + 256 * i];
        }
        __syncthreads();
        #pragma unroll
        for (int kk = 0; kk < 2; ++kk) {
            int ks = h2 * 2 + kk;
            bf16x8 ah[2], alo[2];
            #pragma unroll
            for (int mt = 0; mt < 2; ++mt) {
                const float* ap = A + (size_t)(rows_base + mt * 16 + l16) * D + ks * 32 + q * 8;
                float4 v0 = *(const float4*)ap;
                float4 v1 = *(const float4*)(ap + 4);
                float f[8] = {v0.x, v0.y, v0.z, v0.w, v1.x, v1.y, v1.z, v1.w};
                #pragma unroll
                for (int j = 0; j < 8; ++j) {
                    unsigned short hb = bf16_rne(f[j]);
                    float hf = __uint_as_float(((unsigned)hb) << 16);
                    ah[mt][j]  = (short)hb;
                    alo[mt][j] = (short)bf16_rne(f[j] - hf);
                }
            }
            #pragma unroll
            for (int nt = 0; nt < 8; ++nt) {
                int idx = (((kk * 4 + q) * 128) + nt * 16 + l16) * 8;
                bf16x8 bh = *(const bf16x8*)(bsh + idx);
                bf16x8 bl = *(const bf16x8*)(bsl + idx);
                #pragma unroll
                for (int mt = 0; mt < 2; ++mt) {
                    acc[mt][nt] = __builtin_amdgcn_mfma_f32_16x16x32_bf16(bh, ah[mt], acc[mt][nt], 0, 0, 0);
                    acc[mt][nt] = __builtin_amdgcn_mfma_f32_16x16x32_bf16(bl, ah[mt], acc[mt][nt], 0, 0, 0);
                    acc[mt][nt] = __builtin_amdgcn_mfma_f32_16x16x32_bf16(bh, alo[mt], acc[mt][nt], 0, 0, 0);
                }
            }
        }
    }

    // acc[mt][nt][r]: row = rows_base + mt*16 + l16, col = nt*16 + q*4 + r

    // als/ald: per-lane partial dot over the lane's 32 cols, reduce over q.
    float av[8][4], dv[8][4];
    #pragma unroll
    for (int nt = 0; nt < 8; ++nt) {
        float4 a4 = *(const float4*)(a_s + nt * 16 + q * 4);
        float4 d4 = *(const float4*)(a_d + nt * 16 + q * 4);
        av[nt][0] = a4.x; av[nt][1] = a4.y; av[nt][2] = a4.z; av[nt][3] = a4.w;
        dv[nt][0] = d4.x; dv[nt][1] = d4.y; dv[nt][2] = d4.z; dv[nt][3] = d4.w;
    }
    #pragma unroll
    for (int mt = 0; mt < 2; ++mt) {
        float ps = 0.f, pd = 0.f;
        #pragma unroll
        for (int nt = 0; nt < 8; ++nt) {
            #pragma unroll
            for (int r = 0; r < 4; ++r) {
                float v = acc[mt][nt][r];
                ps += v * av[nt][r];
                pd += v * dv[nt][r];
            }
        }
        ps += __shfl_xor(ps, 16); pd += __shfl_xor(pd, 16);
        ps += __shfl_xor(ps, 32); pd += __shfl_xor(pd, 32);
        if (q == 0) {
            als[rows_base + mt * 16 + l16] = ps;
            ald[rows_base + mt * 16 + l16] = pd;
        }
    }

    // Hb: per-wave LDS transpose (8KB region each), XOR-swizzled to dodge the
    // 256B-stride bank conflict, then 8 fully-coalesced 16B stores per lane.
    __syncthreads();               // everyone done reading B from LDS
    char* tb = (char*)Bs + wave * 8192;
    #pragma unroll
    for (int mt = 0; mt < 2; ++mt) {
        int row = mt * 16 + l16;
        unsigned key = (unsigned)(row & 7) << 4;
        #pragma unroll
        for (int nt = 0; nt < 8; ++nt) {
            ushort4 pk;
            pk.x = bf16_rne(acc[mt][nt][0]);
            pk.y = bf16_rne(acc[mt][nt][1]);
            pk.z = bf16_rne(acc[mt][nt][2]);
            pk.w = bf16_rne(acc[mt][nt][3]);
            unsigned byteoff = (unsigned)row * 256u + (unsigned)(nt * 16 + q * 4) * 2u;
            *(ushort4*)(tb + (byteoff ^ key)) = pk;
        }
    }
    __syncthreads();               // writes visible (wave-local, but cheap & safe)
    #pragma unroll
    for (int i = 0; i < 8; ++i) {
        int m = lane + 64 * i;
        unsigned row = (unsigned)m >> 4;
        unsigned byteoff = (unsigned)m * 16u;
        unsigned addr = byteoff ^ ((row & 7u) << 4);
        int4 v = *(const int4*)(tb + addr);
        *(int4*)((char*)Hb + (size_t)rows_base * 256 + (size_t)m * 16) = v;
    }
}

// Fused softmax + weighted gather. 16 lanes (quarter-wave) per dst node; each
// lane owns 8 cols (one dwordx4 of bf16 per gathered row). Fast path deg<=16.
// Output always fp32 (next GEMM splits inline).
__global__ __launch_bounds__(256) void k_aggr_fused(const ushort_t* __restrict__ hb,
        const float* __restrict__ als, const float* __restrict__ ald,
        const int4* __restrict__ edata, const int* __restrict__ rp,
        const float* __restrict__ bias, int lsel, float* __restrict__ out_f32) {
    int t = threadIdx.x;
    int lane = t & 63;
    int l16 = lane & 15;
    int qb = lane & 48;                 // quarter base within wave
    int n = blockIdx.x * 16 + (t >> 4); // one node per 16 threads
    int s = rp[n], e = rp[n + 1];
    int deg = e - s;
    float aldd = ald[n];
    float alsn = als[n];
    float inv_deg = (deg > 0) ? 1.f / (float)deg : 0.f;

    int4 hvp = *(const int4*)(hb + (size_t)n * D + l16 * 8);
    float acc8[8];

    if (deg <= 16) {
        int sn0 = 0;
        float al0 = -1e30f, alev0 = 0.f;
        if (l16 < deg) {
            int4 ed = edata[s + l16];
            sn0 = ed.x;
            alev0 = __int_as_float((lsel == 0) ? ed.y : ((lsel == 1) ? ed.z : ed.w));
            al0 = leaky(als[sn0] + aldd + alev0);
        }
        float mm = al0, asum = alev0;
        #pragma unroll
        for (int off = 1; off < 16; off <<= 1) {
            mm = fmaxf(mm, __shfl_xor(mm, off));
            asum += __shfl_xor(asum, off);
        }
        float self_al = leaky(alsn + aldd + asum * inv_deg);
        mm = fmaxf(mm, self_al);
        float p0 = (l16 < deg) ? __expf(al0 - mm) : 0.f;
        float den = p0;
        #pragma unroll
        for (int off = 1; off < 16; off <<= 1) den += __shfl_xor(den, off);
        float es = __expf(self_al - mm);
        den += es;
        float inv = 1.f / den;
        float w0 = p0 * inv;
        float wself = es * inv;

        float fv[8];
        unpack8(hvp, fv);
        #pragma unroll
        for (int j = 0; j < 8; ++j) acc8[j] = wself * fv[j];

        int tt = 0;
        for (; tt + 4 <= deg; tt += 4) {
            int   sA = __shfl(sn0, qb + tt),     sB = __shfl(sn0, qb + tt + 1);
            int   sC = __shfl(sn0, qb + tt + 2), sD = __shfl(sn0, qb + tt + 3);
            float wA = __shfl(w0, qb + tt),      wB = __shfl(w0, qb + tt + 1);
            float wC = __shfl(w0, qb + tt + 2),  wD = __shfl(w0, qb + tt + 3);
            int4 rA = *(const int4*)(hb + (size_t)sA * D + l16 * 8);
            int4 rB = *(const int4*)(hb + (size_t)sB * D + l16 * 8);
            int4 rC = *(const int4*)(hb + (size_t)sC * D + l16 * 8);
            int4 rD = *(const int4*)(hb + (size_t)sD * D + l16 * 8);
            float fA[8], fB[8], fC[8], fD[8];
            unpack8(rA, fA); unpack8(rB, fB); unpack8(rC, fC); unpack8(rD, fD);
            #pragma unroll
            for (int j = 0; j < 8; ++j)
                acc8[j] += wA * fA[j] + wB * fB[j] + wC * fC[j] + wD * fD[j];
        }
        for (; tt < deg; ++tt) {
            int st = __shfl(sn0, qb + tt);
            float wt = __shfl(w0, qb + tt);
            int4 r = *(const int4*)(hb + (size_t)st * D + l16 * 8);
            float f[8];
            unpack8(r, f);
            #pragma unroll
            for (int j = 0; j < 8; ++j) acc8[j] += wt * f[j];
        }
    } else {
        // general path (rare): chunked 3-pass with recompute
        float mm = -1e30f, asum = 0.f;
        for (int base = s; base < e; base += 16) {
            int j = base + l16;
            if (j < e) {
                int4 ed = edata[j];
                float alev = __int_as_float((lsel == 0) ? ed.y : ((lsel == 1) ? ed.z : ed.w));
                asum += alev;
                mm = fmaxf(mm, leaky(als[ed.x] + aldd + alev));
            }
        }
        #pragma unroll
        for (int off = 1; off < 16; off <<= 1) {
            mm = fmaxf(mm, __shfl_xor(mm, off));
            asum += __shfl_xor(asum, off);
        }
        float self_al = leaky(alsn + aldd + asum * inv_deg);
        mm = fmaxf(mm, self_al);
        float den = 0.f;
        for (int base = s; base < e; base += 16) {
            int j = base + l16;
            if (j < e) {
                int4 ed = edata[j];
                float alev = __int_as_float((lsel == 0) ? ed.y : ((lsel == 1) ? ed.z : ed.w));
                den += __expf(leaky(als[ed.x] + aldd + alev) - mm);
            }
        }
        #pragma unroll
        for (int off = 1; off < 16; off <<= 1) den += __shfl_xor(den, off);
        float es = __expf(self_al - mm);
        den += es;
        float inv = 1.f / den;
        float wself = es * inv;
        float fv[8];
        unpack8(hvp, fv);
        #pragma unroll
        for (int j = 0; j < 8; ++j) acc8[j] = wself * fv[j];
        for (int base = s; base < e; base += 16) {
            int cnt = min(e - base, 16);
            int sn = 0;
            float w = 0.f;
            if (l16 < cnt) {
                int4 ed = edata[base + l16];
                sn = ed.x;
                float alev = __int_as_float((lsel == 0) ? ed.y : ((lsel == 1) ? ed.z : ed.w));
                w = __expf(leaky(als[sn] + aldd + alev) - mm) * inv;
            }
            for (int tt = 0; tt < cnt; ++tt) {
                int st = __shfl(sn, qb + tt);
                float wt = __shfl(w, qb + tt);
                int4 r = *(const int4*)(hb + (size_t)st * D + l16 * 8);
                float f[8];
                unpack8(r, f);
                #pragma unroll
                for (int j = 0; j < 8; ++j) acc8[j] += wt * f[j];
            }
        }
    }

    const float4* b4 = (const float4*)(bias + l16 * 8);
    float4 b0 = b4[0], b1 = b4[1];
    float bb[8] = {b0.x, b0.y, b0.z, b0.w, b1.x, b1.y, b1.z, b1.w};
    float o[8];
    #pragma unroll
    for (int j = 0; j < 8; ++j) o[j] = gelu_exact(acc8[j] + bb[j]);

    float4* o4 = (float4*)(out_f32 + (size_t)n * D + l16 * 8);
    o4[0] = make_float4(o[0], o[1], o[2], o[3]);
    o4[1] = make_float4(o[4], o[5], o[6], o[7]);
}

// ---------------- launch ----------------

extern "C" void kernel_launch(void* const* d_in, const int* in_sizes, int n_in,
                              void* d_out, int out_size, void* d_ws, size_t ws_size,
                              hipStream_t stream) {
    (void)in_sizes; (void)n_in; (void)out_size; (void)ws_size;
    const float* x        = (const float*)d_in[0];
    const int*   eidx     = (const int*)d_in[1];   // [2, NE]: row0=src, row1=dst
    const float* ea       = (const float*)d_in[2];
    const float* Ws       = (const float*)d_in[3];
    const float* att_src  = (const float*)d_in[4];
    const float* att_dst  = (const float*)d_in[5];
    const float* W_edge   = (const float*)d_in[6];
    const float* att_edge = (const float*)d_in[7];
    const float* bias     = (const float*)d_in[8];
    float* out = (float*)d_out;

    char* ws = (char*)d_ws;
    size_t off = 0;
    auto alloc = [&](size_t bytes) {
        void* p = ws + off;
        off += (bytes + 255) & ~(size_t)255;
        return p;
    };
    ushort_t* Hb   = (ushort_t*)alloc((size_t)NN * D * 2);  // bf16 h after GEMM (gather input)
    float*    Hx   = (float*)alloc((size_t)NN * D * 4);     // fp32 activations between layers
    float*    als  = (float*)alloc((size_t)NN * 4);
    float*    ald  = (float*)alloc((size_t)NN * 4);
    int4*     edata= (int4*)alloc((size_t)NE * 16);         // (src, ale0, ale1, ale2)
    float*    ale0 = (float*)alloc((size_t)NE * 4);         // edge-order ale per layer
    float*    ale1 = (float*)alloc((size_t)NE * 4);
    float*    ale2 = (float*)alloc((size_t)NE * 4);
    float*    wvec = (float*)alloc(3 * ED * 4);
    int*      deg  = (int*)alloc((size_t)NN * 4);
    int*      rp   = (int*)alloc((size_t)(NN + 4) * 4);
    int*      cursor = (int*)alloc((size_t)NN * 4);
    int*      bsum = (int*)alloc(256 * 4);
    int*      bscan= (int*)alloc(256 * 4);
    short*    Whp  = (short*)alloc((size_t)3 * D * D * 2);
    short*    Wlp  = (short*)alloc((size_t)3 * D * D * 2);

    const int* e_src = eidx;
    const int* e_dst = eidx + NE;

    // CSR build + edge precompute
    hipMemsetAsync(deg, 0, (size_t)NN * 4, stream);
    k_wvec<<<1, 128, 0, stream>>>(W_edge, att_edge, wvec);
    k_ale_hist<<<NE / 256, 256, 0, stream>>>(ea, wvec, e_dst, deg, ale0, ale1, ale2);
    k_scan1<<<NN / 256, 256, 0, stream>>>(deg, rp, bsum);
    k_scan2<<<1, 256, 0, stream>>>(bsum, bscan, rp);
    k_scan3<<<NN / 256, 256, 0, stream>>>(rp, bscan, cursor);
    k_scatter4<<<NE / 1024, 256, 0, stream>>>(e_src, e_dst, cursor, ale0, ale1, ale2, edata);

    // weight precompute
    k_wpack<<<24, 256, 0, stream>>>(Ws, Whp, Wlp);

    // layers (GEMM reads fp32 and splits to bf16 hi/lo inline)
    for (int l = 0; l < 3; ++l) {
        k_gemm_mfma<<<NN / 128, 256, 0, stream>>>(l == 0 ? x : Hx,
                                                  Whp + (size_t)l * D * D, Wlp + (size_t)l * D * D,
                                                  att_src + (size_t)l * D, att_dst + (size_t)l * D,
                                                  Hb, als, ald);
        bool last = (l == 2);
        k_aggr_fused<<<NN / 16, 256, 0, stream>>>(Hb, als, ald, edata, rp, bias + (size_t)l * D, l,
                                                  last ? out : Hx);
    }
}

// Round 2
// 351.117 us; speedup vs baseline: 1.0448x; 1.0032x over previous
//
#include <hip/hip_runtime.h>
#include <math.h>

#define NN 65536        // nodes
#define NE 524288       // edges (without self loops)
#define D 128
#define ED 32
#define NEG_SLOPE 0.2f

typedef short bf16x8 __attribute__((ext_vector_type(8)));
typedef float f32x4 __attribute__((ext_vector_type(4)));
typedef unsigned short ushort_t;

__device__ __forceinline__ float leaky(float x) { return x > 0.f ? x : NEG_SLOPE * x; }
__device__ __forceinline__ float gelu_exact(float x) {
    return 0.5f * x * (1.f + erff(x * 0.70710678118654752440f));
}
__device__ __forceinline__ unsigned short bf16_rne(float x) {
    unsigned u = __float_as_uint(x);
    return (unsigned short)((u + 0x7FFFu + ((u >> 16) & 1u)) >> 16);
}
__device__ __forceinline__ void unpack8(int4 r, float* f) {
    unsigned u0 = (unsigned)r.x, u1 = (unsigned)r.y, u2 = (unsigned)r.z, u3 = (unsigned)r.w;
    f[0] = __uint_as_float(u0 << 16); f[1] = __uint_as_float(u0 & 0xFFFF0000u);
    f[2] = __uint_as_float(u1 << 16); f[3] = __uint_as_float(u1 & 0xFFFF0000u);
    f[4] = __uint_as_float(u2 << 16); f[5] = __uint_as_float(u2 & 0xFFFF0000u);
    f[6] = __uint_as_float(u3 << 16); f[7] = __uint_as_float(u3 & 0xFFFF0000u);
}

// ---------------- front: fused {ale_hist (wvec inline) | wpack} ----------------
// ale blocks: 0..2047; wpack blocks: 2048..2071. wvec (96 dots of len 128) is
// recomputed per ale-block into LDS — removes the k_wvec launch and the
// in-kernel ordering hazard. We/ae are L2-hot after the first blocks.

__global__ __launch_bounds__(256) void k_front(const float* __restrict__ ea,
        const int* __restrict__ dstArr, int* __restrict__ deg,
        const float* __restrict__ We, const float* __restrict__ ae,
        const float* __restrict__ Ws, short* __restrict__ Whp, short* __restrict__ Wlp,
        float* __restrict__ ale0, float* __restrict__ ale1, float* __restrict__ ale2) {
    if (blockIdx.x >= NE / 256) {
        // ---- wpack role: pack W into MFMA fragment order, split bf16 hi/lo ----
        int t = (blockIdx.x - NE / 256) * 256 + threadIdx.x;
        if (t >= 3 * 4 * 4 * 128) return;
        int n = t & 127;
        int q = (t >> 7) & 3;
        int ks = (t >> 9) & 3;
        int l = t >> 11;
        const float* w = Ws + (size_t)l * D * D;
        size_t obase = (size_t)l * D * D + ((size_t)((ks * 4 + q) * 128) + n) * 8;
        #pragma unroll
        for (int j = 0; j < 8; ++j) {
            float x = w[(size_t)(ks * 32 + q * 8 + j) * D + n];
            unsigned short hb = bf16_rne(x);
            float hf = __uint_as_float(((unsigned)hb) << 16);
            Whp[obase + j] = (short)hb;
            Wlp[obase + j] = (short)bf16_rne(x - hf);
        }
        return;
    }
    // ---- ale role ----
    __shared__ __align__(16) float wv[3 * ED];
    int t = threadIdx.x;
    if (t < 3 * ED) {
        int l = t >> 5, k = t & 31;
        const float4* w = (const float4*)(We + (size_t)(l * ED + k) * D);
        const float4* a = (const float4*)(ae + (size_t)l * D);
        float s = 0.f;
        #pragma unroll
        for (int i = 0; i < D / 4; ++i) {
            float4 x = w[i], y = a[i];
            s += x.x * y.x + x.y * y.y + x.z * y.z + x.w * y.w;
        }
        wv[t] = s;
    }
    __syncthreads();
    int e = blockIdx.x * 256 + t;
    atomicAdd(&deg[dstArr[e]], 1);
    const float4* row = (const float4*)(ea + (size_t)e * ED);
    const float4* w0 = (const float4*)(wv);
    const float4* w1 = (const float4*)(wv + ED);
    const float4* w2 = (const float4*)(wv + 2 * ED);
    float s0 = 0.f, s1 = 0.f, s2 = 0.f;
    #pragma unroll
    for (int i = 0; i < ED / 4; ++i) {
        float4 v = row[i];
        float4 a = w0[i], b = w1[i], c = w2[i];
        s0 += v.x * a.x + v.y * a.y + v.z * a.z + v.w * a.w;
        s1 += v.x * b.x + v.y * b.y + v.z * b.z + v.w * b.w;
        s2 += v.x * c.x + v.y * c.y + v.z * c.z + v.w * c.w;
    }
    ale0[e] = s0;
    ale1[e] = s1;
    ale2[e] = s2;
}

// ---------------- scan (2 kernels) ----------------

__global__ void k_scan1(const int* __restrict__ deg, int* __restrict__ rp, int* __restrict__ bsum) {
    __shared__ int s[256];
    int t = threadIdx.x;
    int i = blockIdx.x * 256 + t;
    int v = deg[i];
    s[t] = v;
    __syncthreads();
    #pragma unroll
    for (int off = 1; off < 256; off <<= 1) {
        int x = (t >= off) ? s[t - off] : 0;
        __syncthreads();
        s[t] += x;
        __syncthreads();
    }
    rp[i] = s[t] - v;
    if (t == 255) bsum[blockIdx.x] = s[t];
}

// finalize: every block re-scans bsum in LDS, adds its exclusive block prefix,
// writes rp and cursor. rp[NN] = NE (known constant).
__global__ void k_scanF(int* __restrict__ rp, const int* __restrict__ bsum, int* __restrict__ cursor) {
    __shared__ int s[256];
    int t = threadIdx.x;
    int bid = blockIdx.x;
    int v = bsum[t];
    s[t] = v;
    __syncthreads();
    #pragma unroll
    for (int off = 1; off < 256; off <<= 1) {
        int x = (t >= off) ? s[t - off] : 0;
        __syncthreads();
        s[t] += x;
        __syncthreads();
    }
    int add = (bid > 0) ? s[bid - 1] : 0;
    int i = bid * 256 + t;
    int r = rp[i] + add;
    rp[i] = r;
    cursor[i] = r;
    if (bid == 255 && t == 255) rp[NN] = NE;
}

// ---------------- shared GEMM body ----------------
// C = A @ W via split-bf16 MFMA, swapped operands: mfma(W_frag, h_frag).
// 16 rows per wave, 64 rows per block (1024 gemm blocks -> 4 waves/SIMD).
// A read fp32, split bf16 hi/lo inline. W staged in LDS (32KB, two halves).
// Epilogue: Hb bf16 via per-wave swizzled LDS transpose -> coalesced stores;
// als/ald per-lane dots + 2 shuffles.

__device__ __forceinline__ void gemm_body(int b, const float* __restrict__ A,
        const short* __restrict__ Whp, const short* __restrict__ Wlp,
        const float* __restrict__ a_s, const float* __restrict__ a_d,
        ushort_t* __restrict__ Hb, float* __restrict__ als, float* __restrict__ ald) {
    __shared__ int4 Bs[2048];   // 32KB: [0..1023]=hi, [1024..2047]=lo; reused for transpose
    int t = threadIdx.x;
    int wave = t >> 6, lane = t & 63;
    int l16 = lane & 15, q = lane >> 4;
    int rows_base = b * 64 + wave * 16;

    const int4* wh4 = (const int4*)Whp;
    const int4* wl4 = (const int4*)Wlp;
    const short* bsh = (const short*)Bs;
    const short* bsl = (const short*)(Bs + 1024);

    f32x4 acc[8] = {};
    #pragma unroll
    for (int h2 = 0; h2 < 2; ++h2) {
        if (h2) __syncthreads();
        #pragma unroll
        for (int i = 0; i < 4; ++i) {
            Bs[t + 256 * i] = wh4[h2 * 1024 + t + 256 * i];
            Bs[1024 + t + 256 * i] = wl4[h2 * 1024 + t + 256 * i];
        }
        __syncthreads();
        #pragma unroll
        for (int kk = 0; kk < 2; ++kk) {
            int ks = h2 * 2 + kk;
            const float* ap = A + (size_t)(rows_base + l16) * D + ks * 32 + q * 8;
            float4 v0 = *(const float4*)ap;
            float4 v1 = *(const float4*)(ap + 4);
            float f[8] = {v0.x, v0.y, v0.z, v0.w, v1.x, v1.y, v1.z, v1.w};
            bf16x8 ah, alo;
            #pragma unroll
            for (int j = 0; j < 8; ++j) {
                unsigned short hb = bf16_rne(f[j]);
                float hf = __uint_as_float(((unsigned)hb) << 16);
                ah[j]  = (short)hb;
                alo[j] = (short)bf16_rne(f[j] - hf);
            }
            #pragma unroll
            for (int nt = 0; nt < 8; ++nt) {
                int idx = (((kk * 4 + q) * 128) + nt * 16 + l16) * 8;
                bf16x8 bh = *(const bf16x8*)(bsh + idx);
                bf16x8 bl = *(const bf16x8*)(bsl + idx);
                acc[nt] = __builtin_amdgcn_mfma_f32_16x16x32_bf16(bh, ah, acc[nt], 0, 0, 0);
                acc[nt] = __builtin_amdgcn_mfma_f32_16x16x32_bf16(bl, ah, acc[nt], 0, 0, 0);
                acc[nt] = __builtin_amdgcn_mfma_f32_16x16x32_bf16(bh, alo, acc[nt], 0, 0, 0);
            }
        }
    }

    // acc[nt][r]: row = rows_base + l16, col = nt*16 + q*4 + r
    float ps = 0.f, pd = 0.f;
    #pragma unroll
    for (int nt = 0; nt < 8; ++nt) {
        float4 a4 = *(const float4*)(a_s + nt * 16 + q * 4);
        float4 d4 = *(const float4*)(a_d + nt * 16 + q * 4);
        ps += acc[nt][0] * a4.x + acc[nt][1] * a4.y + acc[nt][2] * a4.z + acc[nt][3] * a4.w;
        pd += acc[nt][0] * d4.x + acc[nt][1] * d4.y + acc[nt][2] * d4.z + acc[nt][3] * d4.w;
    }
    ps += __shfl_xor(ps, 16); pd += __shfl_xor(pd, 16);
    ps += __shfl_xor(ps, 32); pd += __shfl_xor(pd, 32);
    if (q == 0) {
        als[rows_base + l16] = ps;
        ald[rows_base + l16] = pd;
    }

    // Hb: per-wave 4KB LDS transpose, XOR-swizzled, then coalesced 16B stores.
    __syncthreads();               // all waves done reading B fragments
    char* tb = (char*)Bs + wave * 4096;
    {
        int row = l16;
        unsigned key = (unsigned)(row & 7) << 4;
        #pragma unroll
        for (int nt = 0; nt < 8; ++nt) {
            ushort4 pk;
            pk.x = bf16_rne(acc[nt][0]);
            pk.y = bf16_rne(acc[nt][1]);
            pk.z = bf16_rne(acc[nt][2]);
            pk.w = bf16_rne(acc[nt][3]);
            unsigned byteoff = (unsigned)row * 256u + (unsigned)(nt * 16 + q * 4) * 2u;
            *(ushort4*)(tb + (byteoff ^ key)) = pk;
        }
    }
    __syncthreads();
    #pragma unroll
    for (int i = 0; i < 4; ++i) {
        int m = lane + 64 * i;
        unsigned row = (unsigned)m >> 4;
        unsigned byteoff = (unsigned)m * 16u;
        unsigned addr = byteoff ^ ((row & 7u) << 4);
        int4 v = *(const int4*)(tb + addr);
        *(int4*)((char*)Hb + (size_t)rows_base * 256 + (size_t)m * 16) = v;
    }
}

// Fused {scatter (blocks 0..255) | layer-0 GEMM (blocks 256..1279)} — fully
// independent work, runs concurrently in one dispatch.
__global__ __launch_bounds__(256) void k_scatgemm(
        const int* __restrict__ srcArr, const int* __restrict__ dstArr,
        int* __restrict__ cursor, const float* __restrict__ ale0,
        const float* __restrict__ ale1, const float* __restrict__ ale2,
        int4* __restrict__ edata,
        const float* __restrict__ A, const short* __restrict__ Whp,
        const short* __restrict__ Wlp, const float* __restrict__ a_s,
        const float* __restrict__ a_d, ushort_t* __restrict__ Hb,
        float* __restrict__ als, float* __restrict__ ald) {
    if (blockIdx.x < 256) {
        // scatter role: 8 edges per thread for 8x MLP on atomic + random store
        int base = blockIdx.x * 2048 + threadIdx.x;
        int e[8], d[8], p[8];
        #pragma unroll
        for (int i = 0; i < 8; ++i) e[i] = base + 256 * i;
        #pragma unroll
        for (int i = 0; i < 8; ++i) d[i] = dstArr[e[i]];
        #pragma unroll
        for (int i = 0; i < 8; ++i) p[i] = atomicAdd(&cursor[d[i]], 1);
        #pragma unroll
        for (int i = 0; i < 8; ++i) {
            edata[p[i]] = make_int4(srcArr[e[i]], __float_as_int(ale0[e[i]]),
                                    __float_as_int(ale1[e[i]]), __float_as_int(ale2[e[i]]));
        }
        return;
    }
    gemm_body(blockIdx.x - 256, A, Whp, Wlp, a_s, a_d, Hb, als, ald);
}

__global__ __launch_bounds__(256) void k_gemm(const float* __restrict__ A,
        const short* __restrict__ Whp, const short* __restrict__ Wlp,
        const float* __restrict__ a_s, const float* __restrict__ a_d,
        ushort_t* __restrict__ Hb, float* __restrict__ als, float* __restrict__ ald) {
    gemm_body(blockIdx.x, A, Whp, Wlp, a_s, a_d, Hb, als, ald);
}

// ---------------- fused softmax + weighted gather ----------------
// 16 lanes per dst node. Fast path deg<=16: 8-deep pre-issued gather pipeline
// (weights are exactly 0 beyond deg, addresses clamped to a valid row, so the
// always-load batch adds no error). Output fp32 (next GEMM splits inline).

__global__ __launch_bounds__(256) void k_aggr_fused(const ushort_t* __restrict__ hb,
        const float* __restrict__ als, const float* __restrict__ ald,
        const int4* __restrict__ edata, const int* __restrict__ rp,
        const float* __restrict__ bias, int lsel, float* __restrict__ out_f32) {
    int t = threadIdx.x;
    int lane = t & 63;
    int l16 = lane & 15;
    int qb = lane & 48;                 // quarter base within wave
    int n = blockIdx.x * 16 + (t >> 4); // one node per 16 threads
    int s = rp[n], e = rp[n + 1];
    int deg = e - s;
    float aldd = ald[n];
    float alsn = als[n];
    float inv_deg = (deg > 0) ? 1.f / (float)deg : 0.f;

    int4 hvp = *(const int4*)(hb + (size_t)n * D + l16 * 8);
    float acc8[8];

    if (deg <= 16) {
        int sn0 = 0;
        float al0 = -1e30f, alev0 = 0.f;
        if (l16 < deg) {
            int4 ed = edata[s + l16];
            sn0 = ed.x;
            alev0 = __int_as_float((lsel == 0) ? ed.y : ((lsel == 1) ? ed.z : ed.w));
            al0 = leaky(als[sn0] + aldd + alev0);
        }
        float mm = al0, asum = alev0;
        #pragma unroll
        for (int off = 1; off < 16; off <<= 1) {
            mm = fmaxf(mm, __shfl_xor(mm, off));
            asum += __shfl_xor(asum, off);
        }
        float self_al = leaky(alsn + aldd + asum * inv_deg);
        mm = fmaxf(mm, self_al);
        float p0 = (l16 < deg) ? __expf(al0 - mm) : 0.f;
        float den = p0;
        #pragma unroll
        for (int off = 1; off < 16; off <<= 1) den += __shfl_xor(den, off);
        float es = __expf(self_al - mm);
        den += es;
        float inv = 1.f / den;
        float w0 = p0 * inv;       // exactly 0 for l16 >= deg
        float wself = es * inv;

        float fv[8];
        unpack8(hvp, fv);
        #pragma unroll
        for (int j = 0; j < 8; ++j) acc8[j] = wself * fv[j];

        // batch 1: edges 0..7 (always; zero-weight terms are exact no-ops)
        int sA[8]; float wA[8]; int4 rb[8];
        #pragma unroll
        for (int i = 0; i < 8; ++i) { sA[i] = __shfl(sn0, qb + i); wA[i] = __shfl(w0, qb + i); }
        #pragma unroll
        for (int i = 0; i < 8; ++i) rb[i] = *(const int4*)(hb + (size_t)sA[i] * D + l16 * 8);

        // batch 2: edges 8..15 (issued before batch-1 consumption)
        int sB[8]; float wB[8]; int4 rb2[8];
        #pragma unroll
        for (int i = 0; i < 8; ++i) { sB[i] = __shfl(sn0, qb + 8 + i); wB[i] = __shfl(w0, qb + 8 + i); }
        bool more = (deg > 8);
        if (more) {
            #pragma unroll
            for (int i = 0; i < 8; ++i) rb2[i] = *(const int4*)(hb + (size_t)sB[i] * D + l16 * 8);
        }

        #pragma unroll
        for (int i = 0; i < 8; ++i) {
            float f[8];
            unpack8(rb[i], f);
            #pragma unroll
            for (int j = 0; j < 8; ++j) acc8[j] += wA[i] * f[j];
        }
        if (more) {
            #pragma unroll
            for (int i = 0; i < 8; ++i) {
                float f[8];
                unpack8(rb2[i], f);
                #pragma unroll
                for (int j = 0; j < 8; ++j) acc8[j] += wB[i] * f[j];
            }
        }
    } else {
        // general path (rare): chunked 3-pass with recompute
        float mm = -1e30f, asum = 0.f;
        for (int base = s; base < e; base += 16) {
            int j = base + l16;
            if (j < e) {
                int4 ed = edata[j];
                float alev = __int_as_float((lsel == 0) ? ed.y : ((lsel == 1) ? ed.z : ed.w));
                asum += alev;
                mm = fmaxf(mm, leaky(als[ed.x] + aldd + alev));
            }
        }
        #pragma unroll
        for (int off = 1; off < 16; off <<= 1) {
            mm = fmaxf(mm, __shfl_xor(mm, off));
            asum += __shfl_xor(asum, off);
        }
        float self_al = leaky(alsn + aldd + asum * inv_deg);
        mm = fmaxf(mm, self_al);
        float den = 0.f;
        for (int base = s; base < e; base += 16) {
            int j = base + l16;
            if (j < e) {
                int4 ed = edata[j];
                float alev = __int_as_float((lsel == 0) ? ed.y : ((lsel == 1) ? ed.z : ed.w));
                den += __expf(leaky(als[ed.x] + aldd + alev) - mm);
            }
        }
        #pragma unroll
        for (int off = 1; off < 16; off <<= 1) den += __shfl_xor(den, off);
        float es = __expf(self_al - mm);
        den += es;
        float inv = 1.f / den;
        float wself = es * inv;
        float fv[8];
        unpack8(hvp, fv);
        #pragma unroll
        for (int j = 0; j < 8; ++j) acc8[j] = wself * fv[j];
        for (int base = s; base < e; base += 16) {
            int cnt = min(e - base, 16);
            int sn = 0;
            float w = 0.f;
            if (l16 < cnt) {
                int4 ed = edata[base + l16];
                sn = ed.x;
                float alev = __int_as_float((lsel == 0) ? ed.y : ((lsel == 1) ? ed.z : ed.w));
                w = __expf(leaky(als[sn] + aldd + alev) - mm) * inv;
            }
            for (int tt = 0; tt < cnt; ++tt) {
                int st = __shfl(sn, qb + tt);
                float wt = __shfl(w, qb + tt);
                int4 r = *(const int4*)(hb + (size_t)st * D + l16 * 8);
                float f[8];
                unpack8(r, f);
                #pragma unroll
                for (int j = 0; j < 8; ++j) acc8[j] += wt * f[j];
            }
        }
    }

    const float4* b4 = (const float4*)(bias + l16 * 8);
    float4 b0 = b4[0], b1 = b4[1];
    float bb[8] = {b0.x, b0.y, b0.z, b0.w, b1.x, b1.y, b1.z, b1.w};
    float o[8];
    #pragma unroll
    for (int j = 0; j < 8; ++j) o[j] = gelu_exact(acc8[j] + bb[j]);

    float4* o4 = (float4*)(out_f32 + (size_t)n * D + l16 * 8);
    o4[0] = make_float4(o[0], o[1], o[2], o[3]);
    o4[1] = make_float4(o[4], o[5], o[6], o[7]);
}

// ---------------- launch ----------------

extern "C" void kernel_launch(void* const* d_in, const int* in_sizes, int n_in,
                              void* d_out, int out_size, void* d_ws, size_t ws_size,
                              hipStream_t stream) {
    (void)in_sizes; (void)n_in; (void)out_size; (void)ws_size;
    const float* x        = (const float*)d_in[0];
    const int*   eidx     = (const int*)d_in[1];   // [2, NE]: row0=src, row1=dst
    const float* ea       = (const float*)d_in[2];
    const float* Ws       = (const float*)d_in[3];
    const float* att_src  = (const float*)d_in[4];
    const float* att_dst  = (const float*)d_in[5];
    const float* W_edge   = (const float*)d_in[6];
    const float* att_edge = (const float*)d_in[7];
    const float* bias     = (const float*)d_in[8];
    float* out = (float*)d_out;

    char* ws = (char*)d_ws;
    size_t off = 0;
    auto alloc = [&](size_t bytes) {
        void* p = ws + off;
        off += (bytes + 255) & ~(size_t)255;
        return p;
    };
    ushort_t* Hb   = (ushort_t*)alloc((size_t)NN * D * 2);  // bf16 h after GEMM (gather input)
    float*    Hx   = (float*)alloc((size_t)NN * D * 4);     // fp32 activations between layers
    float*    als  = (float*)alloc((size_t)NN * 4);
    float*    ald  = (float*)alloc((size_t)NN * 4);
    int4*     edata= (int4*)alloc((size_t)NE * 16);         // (src, ale0, ale1, ale2)
    float*    ale0 = (float*)alloc((size_t)NE * 4);         // edge-order ale per layer
    float*    ale1 = (float*)alloc((size_t)NE * 4);
    float*    ale2 = (float*)alloc((size_t)NE * 4);
    int*      deg  = (int*)alloc((size_t)NN * 4);
    int*      rp   = (int*)alloc((size_t)(NN + 4) * 4);
    int*      cursor = (int*)alloc((size_t)NN * 4);
    int*      bsum = (int*)alloc(256 * 4);
    short*    Whp  = (short*)alloc((size_t)3 * D * D * 2);
    short*    Wlp  = (short*)alloc((size_t)3 * D * D * 2);

    const int* e_src = eidx;
    const int* e_dst = eidx + NE;

    // CSR build + edge precompute + weight pack (fused front)
    hipMemsetAsync(deg, 0, (size_t)NN * 4, stream);
    k_front<<<NE / 256 + 24, 256, 0, stream>>>(ea, e_dst, deg, W_edge, att_edge,
                                               Ws, Whp, Wlp, ale0, ale1, ale2);
    k_scan1<<<NN / 256, 256, 0, stream>>>(deg, rp, bsum);
    k_scanF<<<NN / 256, 256, 0, stream>>>(rp, bsum, cursor);

    // scatter || layer-0 GEMM (independent)
    k_scatgemm<<<256 + NN / 64, 256, 0, stream>>>(e_src, e_dst, cursor, ale0, ale1, ale2, edata,
                                                  x, Whp, Wlp, att_src, att_dst, Hb, als, ald);

    // layers
    for (int l = 0; l < 3; ++l) {
        if (l > 0) {
            k_gemm<<<NN / 64, 256, 0, stream>>>(Hx, Whp + (size_t)l * D * D, Wlp + (size_t)l * D * D,
                                                att_src + (size_t)l * D, att_dst + (size_t)l * D,
                                                Hb, als, ald);
        }
        bool last = (l == 2);
        k_aggr_fused<<<NN / 16, 256, 0, stream>>>(Hb, als, ald, edata, rp, bias + (size_t)l * D, l,
                                                  last ? out : Hx);
    }
}